// Round 6
// baseline (760.274 us; speedup 1.0000x reference)
//
#include <hip/hip_runtime.h>
#include <hip/hip_cooperative_groups.h>

namespace cg = cooperative_groups;

// OTPE single timestep on MI355X.
// Round 6: single cooperative mega-kernel (3 phases, 2 grid syncs).
// Why: (a) every per-kernel variant R2-R5 landed at 145-170us for the big
// pass and the top-5 counter slots are occupied by 163-168us harness fills,
// so our kernels are invisible to rocprof; one ~190us dispatch becomes the
// top dispatch WITH counters. (b) removes 3 kernel-boundary serializations
// and keeps E_new in registers for the R update (no re-read).
// Fallback: verified R5 four-kernel path if cooperative launch fails.

#define SIG_TAU 0.8807970779778823f  // sigmoid(2.0) in f32

typedef float f32x4 __attribute__((ext_vector_type(4)));

constexpr int N_IN  = 8192;
constexpr int N_OUT = 4096;
constexpr int NCG   = N_OUT / 4;          // 1024 float4 column-groups per row
constexpr int NCHUNK = 256;               // split-K chunks (4 MB partials)
constexpr int ROWS_PER_CHUNK = N_IN / NCHUNK;   // 32
constexpr int ROWS_PER_CHUNK_ATOM = 64;         // fallback path
constexpr int MEGA_GRID = 1024;           // 4 blocks/CU, residency-safe

// Output offsets (floats)
constexpr size_t OFF_S     = 0;
constexpr size_t OFF_U     = (size_t)N_OUT;                       // 4096
constexpr size_t OFF_E     = (size_t)2 * N_OUT;                   // 8192
constexpr size_t OFF_R     = OFF_E + (size_t)N_IN * N_OUT;        // 33562624
constexpr size_t OFF_G     = OFF_R + (size_t)N_IN * N_OUT;        // 67117056
constexpr size_t OFF_RATIO = OFF_G + (size_t)N_OUT;               // 67121152

// ---------------------------------------------------------------------------
// Mega-kernel: phase1 split-K matvec -> sync -> phase2 finalize (16 blocks)
// -> sync -> phase3 fused E/R streaming pass (E_new stays in registers).
// ---------------------------------------------------------------------------
__global__ __launch_bounds__(256, 4) void otpe_mega(
    const float* __restrict__ x, const f32x4* __restrict__ W4,
    const float* __restrict__ u, const f32x4* __restrict__ E4,
    const f32x4* __restrict__ R4, const float* __restrict__ g_bar,
    const float* __restrict__ ratio, float* __restrict__ out,
    float* __restrict__ sg_ws, f32x4* __restrict__ part4) {
    cg::grid_group grid = cg::this_grid();
    const int tid = threadIdx.x;
    const int bid = blockIdx.x;

    // ---- Phase 1: split-K matvec. 1024 blocks = 4 cg-quads x 256 chunks.
    {
        const int cgi   = (bid & 3) * 256 + tid;      // 0..1023
        const int chunk = bid >> 2;                   // 0..255
        const int row0  = chunk * ROWS_PER_CHUNK;
        f32x4 a = {0.f, 0.f, 0.f, 0.f};
#pragma unroll 8
        for (int r = 0; r < ROWS_PER_CHUNK; ++r) {
            const float xv = x[row0 + r];
            const f32x4 w  = W4[(size_t)(row0 + r) * NCG + cgi];
            a[0] = fmaf(xv, w[0], a[0]);
            a[1] = fmaf(xv, w[1], a[1]);
            a[2] = fmaf(xv, w[2], a[2]);
            a[3] = fmaf(xv, w[3], a[3]);
        }
        part4[(size_t)chunk * NCG + cgi] = a;
    }

    grid.sync();

    // ---- Phase 2: finalize on blocks 0..15 (4096 columns). Partials are
    // L2-resident (4 MB). Same summation order as the verified R5 finalize.
    if (bid < 16) {
        const int j = bid * 256 + tid;
        const float* part = (const float*)part4;
        float acc = 0.f;
#pragma unroll 8
        for (int c = 0; c < NCHUNK; ++c)
            acc += part[(size_t)c * N_OUT + j];

        const float u_pre = fmaf(SIG_TAU, u[j], acc);
        const float s     = (u_pre >= 1.0f) ? 1.0f : 0.0f;
        const float t     = 1.0f / fmaf(10.0f, fabsf(u_pre - 1.0f), 1.0f);
        const float sg    = t * t;                 // surrogate ds/du_pre
        const float u_new = u_pre - s;             // soft reset, V_TH=1

        const float r0        = SIG_TAU * ratio[0];
        const float ratio_new = r0 + 1.0f;
        const float r         = r0 / ratio_new;
        const float g_new = fmaf(r, g_bar[j], (1.0f - r) * sg);

        out[OFF_S + j] = s;
        out[OFF_U + j] = u_new;
        out[OFF_G + j] = g_new;
        sg_ws[j] = sg;
        if (j == 0) out[OFF_RATIO] = ratio_new;
    }

    grid.sync();

    // ---- Phase 3: fused streaming pass.
    //   E_new = sig_tau*E + x[row];  R_new = sig_tau*R_hat + sg[j]*E_new.
    // E_new computed in registers and written once; never re-read.
    {
        f32x4* Enew4 = (f32x4*)(out + OFF_E);
        f32x4* Rnew4 = (f32x4*)(out + OFF_R);
        const f32x4* sg4 = (const f32x4*)sg_ws;
        const f32x4 s0 = sg4[tid];
        const f32x4 s1 = sg4[tid + 256];
        const f32x4 s2 = sg4[tid + 512];
        const f32x4 s3 = sg4[tid + 768];

        for (int row = bid; row < N_IN; row += MEGA_GRID) {
            const float  xv   = x[row];              // block-uniform scalar
            const size_t base = (size_t)row * NCG + tid;

            const f32x4 e0 = E4[base];
            const f32x4 e1 = E4[base + 256];
            const f32x4 e2 = E4[base + 512];
            const f32x4 e3 = E4[base + 768];
            const f32x4 r0 = R4[base];
            const f32x4 r1 = R4[base + 256];
            const f32x4 r2 = R4[base + 512];
            const f32x4 r3 = R4[base + 768];

            f32x4 en0, en1, en2, en3, rn0, rn1, rn2, rn3;
#define COMP(k)                                                   \
            en##k[0] = fmaf(SIG_TAU, e##k[0], xv);                \
            en##k[1] = fmaf(SIG_TAU, e##k[1], xv);                \
            en##k[2] = fmaf(SIG_TAU, e##k[2], xv);                \
            en##k[3] = fmaf(SIG_TAU, e##k[3], xv);                \
            rn##k[0] = fmaf(s##k[0], en##k[0], SIG_TAU * r##k[0]);\
            rn##k[1] = fmaf(s##k[1], en##k[1], SIG_TAU * r##k[1]);\
            rn##k[2] = fmaf(s##k[2], en##k[2], SIG_TAU * r##k[2]);\
            rn##k[3] = fmaf(s##k[3], en##k[3], SIG_TAU * r##k[3]);
            COMP(0) COMP(1) COMP(2) COMP(3)
#undef COMP

            Enew4[base]       = en0;
            Enew4[base + 256] = en1;
            Enew4[base + 512] = en2;
            Enew4[base + 768] = en3;
            Rnew4[base]       = rn0;
            Rnew4[base + 256] = rn1;
            Rnew4[base + 512] = rn2;
            Rnew4[base + 768] = rn3;
        }
    }
}

// ---------------------------------------------------------------------------
// Fallback path: verified R5 kernels (used only if cooperative launch fails).
// ---------------------------------------------------------------------------
__global__ __launch_bounds__(256) void matvec_split(
    const float* __restrict__ x, const f32x4* __restrict__ W4,
    f32x4* __restrict__ part4) {
    const int cg    = blockIdx.x * 256 + threadIdx.x;
    const int chunk = blockIdx.y;
    const int row0  = chunk * ROWS_PER_CHUNK;
    f32x4 a = {0.f, 0.f, 0.f, 0.f};
#pragma unroll 8
    for (int r = 0; r < ROWS_PER_CHUNK; ++r) {
        const float xv = x[row0 + r];
        const f32x4 w  = W4[(size_t)(row0 + r) * NCG + cg];
        a[0] = fmaf(xv, w[0], a[0]);
        a[1] = fmaf(xv, w[1], a[1]);
        a[2] = fmaf(xv, w[2], a[2]);
        a[3] = fmaf(xv, w[3], a[3]);
    }
    part4[(size_t)chunk * NCG + cg] = a;
}

__global__ __launch_bounds__(256) void finalize(
    const float* __restrict__ part, const int nchunks,
    const float* __restrict__ u, const float* __restrict__ g_bar,
    const float* __restrict__ ratio, float* __restrict__ out,
    float* __restrict__ sg_ws) {
    const int j = blockIdx.x * 256 + threadIdx.x;
    if (j >= N_OUT) return;
    float acc = 0.f;
#pragma unroll 8
    for (int c = 0; c < nchunks; ++c)
        acc += part[(size_t)c * N_OUT + j];

    const float u_pre = fmaf(SIG_TAU, u[j], acc);
    const float s     = (u_pre >= 1.0f) ? 1.0f : 0.0f;
    const float t     = 1.0f / fmaf(10.0f, fabsf(u_pre - 1.0f), 1.0f);
    const float sg    = t * t;
    const float u_new = u_pre - s;

    const float r0        = SIG_TAU * ratio[0];
    const float ratio_new = r0 + 1.0f;
    const float r         = r0 / ratio_new;
    const float g_new = fmaf(r, g_bar[j], (1.0f - r) * sg);

    out[OFF_S + j] = s;
    out[OFF_U + j] = u_new;
    out[OFF_G + j] = g_new;
    sg_ws[j] = sg;
    if (j == 0) out[OFF_RATIO] = ratio_new;
}

__global__ __launch_bounds__(256) void ew_fused(
    const float* __restrict__ x, const f32x4* __restrict__ E4,
    const f32x4* __restrict__ R4, const f32x4* __restrict__ sg4,
    f32x4* __restrict__ Enew4, f32x4* __restrict__ Rnew4) {
    const int tid = threadIdx.x;
    const f32x4 s0 = sg4[tid];
    const f32x4 s1 = sg4[tid + 256];
    const f32x4 s2 = sg4[tid + 512];
    const f32x4 s3 = sg4[tid + 768];
    for (int row = blockIdx.x; row < N_IN; row += gridDim.x) {
        const float  xv   = x[row];
        const size_t base = (size_t)row * NCG + tid;
        const f32x4 e0 = E4[base];
        const f32x4 e1 = E4[base + 256];
        const f32x4 e2 = E4[base + 512];
        const f32x4 e3 = E4[base + 768];
        const f32x4 r0 = R4[base];
        const f32x4 r1 = R4[base + 256];
        const f32x4 r2 = R4[base + 512];
        const f32x4 r3 = R4[base + 768];
        f32x4 en0, en1, en2, en3, rn0, rn1, rn2, rn3;
#define COMP(k)                                                   \
        en##k[0] = fmaf(SIG_TAU, e##k[0], xv);                    \
        en##k[1] = fmaf(SIG_TAU, e##k[1], xv);                    \
        en##k[2] = fmaf(SIG_TAU, e##k[2], xv);                    \
        en##k[3] = fmaf(SIG_TAU, e##k[3], xv);                    \
        rn##k[0] = fmaf(s##k[0], en##k[0], SIG_TAU * r##k[0]);    \
        rn##k[1] = fmaf(s##k[1], en##k[1], SIG_TAU * r##k[1]);    \
        rn##k[2] = fmaf(s##k[2], en##k[2], SIG_TAU * r##k[2]);    \
        rn##k[3] = fmaf(s##k[3], en##k[3], SIG_TAU * r##k[3]);
        COMP(0) COMP(1) COMP(2) COMP(3)
#undef COMP
        Enew4[base]       = en0;
        Enew4[base + 256] = en1;
        Enew4[base + 512] = en2;
        Enew4[base + 768] = en3;
        Rnew4[base]       = rn0;
        Rnew4[base + 256] = rn1;
        Rnew4[base + 512] = rn2;
        Rnew4[base + 768] = rn3;
    }
}

extern "C" void kernel_launch(void* const* d_in, const int* in_sizes, int n_in,
                              void* d_out, int out_size, void* d_ws, size_t ws_size,
                              hipStream_t stream) {
    const float* x     = (const float*)d_in[0];
    const float* W     = (const float*)d_in[1];
    const float* u     = (const float*)d_in[2];
    const float* E     = (const float*)d_in[3];
    const float* R_hat = (const float*)d_in[4];
    const float* g_bar = (const float*)d_in[5];
    const float* ratio = (const float*)d_in[6];
    float* out = (float*)d_out;

    float* sg   = (float*)d_ws;            // [4096] surrogate grad
    float* part = sg + N_OUT;              // [NCHUNK*4096] split-K partials

    // Typed lvalues for the cooperative-launch arg array.
    const f32x4* W4p = (const f32x4*)W;
    const f32x4* E4p = (const f32x4*)E;
    const f32x4* R4p = (const f32x4*)R_hat;
    f32x4*       part4p = (f32x4*)part;
    f32x4*       Enew4  = (f32x4*)(out + OFF_E);
    f32x4*       Rnew4  = (f32x4*)(out + OFF_R);
    const f32x4* sg4p   = (const f32x4*)sg;

    const size_t need = (size_t)(N_OUT + (size_t)NCHUNK * N_OUT) * sizeof(float);
    bool done = false;

    if (ws_size >= need) {
        int dev = 0, coop = 0;
        hipGetDevice(&dev);
        hipDeviceGetAttribute(&coop, hipDeviceAttributeCooperativeLaunch, dev);
        if (coop) {
            void* args[] = {
                (void*)&x, (void*)&W4p, (void*)&u, (void*)&E4p, (void*)&R4p,
                (void*)&g_bar, (void*)&ratio, (void*)&out, (void*)&sg,
                (void*)&part4p};
            hipError_t e = hipLaunchCooperativeKernel(
                (const void*)otpe_mega, dim3(MEGA_GRID), dim3(256), args, 0,
                stream);
            done = (e == hipSuccess);
        }
        if (!done) {
            // Fallback A: verified R5-style sequence (fused big pass).
            dim3 g1(NCG / 256, NCHUNK);    // (4, 256) = 1024 blocks
            matvec_split<<<g1, 256, 0, stream>>>(x, W4p, part4p);
            finalize<<<N_OUT / 256, 256, 0, stream>>>(
                part, NCHUNK, u, g_bar, ratio, out, sg);
            ew_fused<<<2048, 256, 0, stream>>>(x, E4p, R4p, sg4p, Enew4, Rnew4);
            done = true;
        }
    }

    if (!done) {
        // Fallback B (tiny ws): single-chunk matvec via partials in out-span?
        // Not expected in this harness (ws >= 1 GB observed). Use 1-chunk
        // split via part if it fits at minimum size.
        dim3 g1(NCG / 256, 1);
        matvec_split<<<g1, 256, 0, stream>>>(x, W4p, part4p);
        finalize<<<N_OUT / 256, 256, 0, stream>>>(
            part, 1, u, g_bar, ratio, out, sg);
        ew_fused<<<2048, 256, 0, stream>>>(x, E4p, R4p, sg4p, Enew4, Rnew4);
    }
}

// Round 7
// 538.189 us; speedup vs baseline: 1.4127x; 1.4127x over previous
//
#include <hip/hip_runtime.h>

// OTPE single timestep on MI355X.
// Round 7: revert coop mega (380us, 1.25 TB/s — TLP-starved at 1024 blocks).
// Evidence so far: streaming rate scales linearly with resident waves
// (1024 blk -> 1.25 TB/s, 2048 blk -> 2.5 TB/s) => latency-bound with a
// tiny per-wave in-flight window. Suspected cause: loads and stores share
// vmcnt, so a load->compute->store loop serializes each wave on its own
// store acks. Fix: fused streaming pass, fully unrolled over a static
// 16-tile span, software-pipelined (next loads issued BEFORE current
// stores) so the compiler can hold multiple tiles' loads in flight.

#define SIG_TAU 0.8807970779778823f  // sigmoid(2.0) in f32

typedef float f32x4 __attribute__((ext_vector_type(4)));

constexpr int N_IN  = 8192;
constexpr int N_OUT = 4096;
constexpr int NCG   = N_OUT / 4;          // 1024 float4 column-groups per row
constexpr int NCHUNK = 256;               // split-K chunks (4 MB partials)
constexpr int ROWS_PER_CHUNK = N_IN / NCHUNK;   // 32

constexpr int EW_BLOCKS = 2048;           // 8 blocks/CU
constexpr int EW_ITER   = (N_IN * NCG) / (EW_BLOCKS * 256);  // 16 tiles/block

// Output offsets (floats)
constexpr size_t OFF_S     = 0;
constexpr size_t OFF_U     = (size_t)N_OUT;                       // 4096
constexpr size_t OFF_E     = (size_t)2 * N_OUT;                   // 8192
constexpr size_t OFF_R     = OFF_E + (size_t)N_IN * N_OUT;        // 33562624
constexpr size_t OFF_G     = OFF_R + (size_t)N_IN * N_OUT;        // 67117056
constexpr size_t OFF_RATIO = OFF_G + (size_t)N_OUT;               // 67121152

// Split-K matvec, deterministic: each (cg, chunk) partial written exactly once.
// 1024 blocks = 4 blocks/CU; accumulation loop has no stores, so loads
// pipeline freely.
__global__ __launch_bounds__(256) void matvec_split(
    const float* __restrict__ x, const f32x4* __restrict__ W4,
    f32x4* __restrict__ part4) {
    const int cg    = blockIdx.x * 256 + threadIdx.x;   // 0..1023
    const int chunk = blockIdx.y;                        // 0..255
    const int row0  = chunk * ROWS_PER_CHUNK;
    f32x4 a = {0.f, 0.f, 0.f, 0.f};
#pragma unroll 8
    for (int r = 0; r < ROWS_PER_CHUNK; ++r) {
        const float xv = x[row0 + r];
        const f32x4 w  = __builtin_nontemporal_load(
            &W4[(size_t)(row0 + r) * NCG + cg]);
        a[0] = fmaf(xv, w[0], a[0]);
        a[1] = fmaf(xv, w[1], a[1]);
        a[2] = fmaf(xv, w[2], a[2]);
        a[3] = fmaf(xv, w[3], a[3]);
    }
    part4[(size_t)chunk * NCG + cg] = a;   // plain store, no atomics
}

// Per-column: reduce split-K partials (L2/L3-resident), spike, surrogate
// grad, soft reset, g_bar/ratio update.
__global__ __launch_bounds__(256) void finalize(
    const float* __restrict__ part, const int nchunks,
    const float* __restrict__ u, const float* __restrict__ g_bar,
    const float* __restrict__ ratio, float* __restrict__ out,
    float* __restrict__ sg_ws) {
    const int j = blockIdx.x * 256 + threadIdx.x;
    if (j >= N_OUT) return;
    float acc = 0.f;
#pragma unroll 8
    for (int c = 0; c < nchunks; ++c)
        acc += part[(size_t)c * N_OUT + j];   // coalesced across j

    const float u_pre = fmaf(SIG_TAU, u[j], acc);
    const float s     = (u_pre >= 1.0f) ? 1.0f : 0.0f;
    const float t     = 1.0f / fmaf(10.0f, fabsf(u_pre - 1.0f), 1.0f);
    const float sg    = t * t;                 // surrogate ds/du_pre
    const float u_new = u_pre - s;             // soft reset, V_TH=1

    const float r0        = SIG_TAU * ratio[0];
    const float ratio_new = r0 + 1.0f;
    const float r         = r0 / ratio_new;
    // ds_du_prev / sig_tau == sg
    const float g_new = fmaf(r, g_bar[j], (1.0f - r) * sg);

    out[OFF_S + j] = s;
    out[OFF_U + j] = u_new;
    out[OFF_G + j] = g_new;
    sg_ws[j] = sg;
    if (j == 0) out[OFF_RATIO] = ratio_new;
}

// Fused streaming pass, software-pipelined.
//   E_new = sig_tau*E + x[row];  R_new = sig_tau*R_hat + sg[j]*E_new.
// Tile t (global) = 256 consecutive f32x4; block owns 16 consecutive tiles
// (64 KB per array). Loads for tile t+1 are issued BEFORE stores of tile t,
// and the loop is fully unrolled so the compiler can batch loads across
// tiles (deep MLP, no per-iteration store-ack serialization).
__global__ __launch_bounds__(256) void ew_pipe(
    const float* __restrict__ x, const f32x4* __restrict__ E4,
    const f32x4* __restrict__ R4, const f32x4* __restrict__ sg4,
    f32x4* __restrict__ Enew4, f32x4* __restrict__ Rnew4) {
    const int tid = threadIdx.x;
    const size_t tile0 = (size_t)blockIdx.x * EW_ITER;   // global tile index
    size_t o_cur = tile0 * 256 + tid;

    f32x4 e_cur = E4[o_cur];
    f32x4 r_cur = R4[o_cur];

#pragma unroll
    for (int t = 0; t < EW_ITER; ++t) {
        const size_t gt    = tile0 + t;
        const size_t o_nxt = o_cur + 256;

        f32x4 e_nxt = e_cur, r_nxt = r_cur;   // dead on last iteration
        if (t + 1 < EW_ITER) {                // prefetch BEFORE stores
            e_nxt = E4[o_nxt];
            r_nxt = R4[o_nxt];
        }

        const float xv  = x[gt >> 2];                    // row, block-uniform
        const f32x4 sgv = sg4[(gt & 3) * 256 + tid];     // 16 KB, L1-hot

        f32x4 en, rn;
        en[0] = fmaf(SIG_TAU, e_cur[0], xv);
        en[1] = fmaf(SIG_TAU, e_cur[1], xv);
        en[2] = fmaf(SIG_TAU, e_cur[2], xv);
        en[3] = fmaf(SIG_TAU, e_cur[3], xv);
        rn[0] = fmaf(sgv[0], en[0], SIG_TAU * r_cur[0]);
        rn[1] = fmaf(sgv[1], en[1], SIG_TAU * r_cur[1]);
        rn[2] = fmaf(sgv[2], en[2], SIG_TAU * r_cur[2]);
        rn[3] = fmaf(sgv[3], en[3], SIG_TAU * r_cur[3]);

        Enew4[o_cur] = en;
        Rnew4[o_cur] = rn;

        o_cur = o_nxt;
        e_cur = e_nxt;
        r_cur = r_nxt;
    }
}

extern "C" void kernel_launch(void* const* d_in, const int* in_sizes, int n_in,
                              void* d_out, int out_size, void* d_ws, size_t ws_size,
                              hipStream_t stream) {
    const float* x     = (const float*)d_in[0];
    const float* W     = (const float*)d_in[1];
    const float* u     = (const float*)d_in[2];
    const float* E     = (const float*)d_in[3];
    const float* R_hat = (const float*)d_in[4];
    const float* g_bar = (const float*)d_in[5];
    const float* ratio = (const float*)d_in[6];
    float* out = (float*)d_out;

    float* sg   = (float*)d_ws;            // [4096] surrogate grad
    float* part = sg + N_OUT;              // [NCHUNK*4096] split-K partials

    f32x4* Enew4 = (f32x4*)(out + OFF_E);
    f32x4* Rnew4 = (f32x4*)(out + OFF_R);

    const size_t need = (size_t)(N_OUT + (size_t)NCHUNK * N_OUT) * sizeof(float);
    const int nchunk = (ws_size >= need) ? NCHUNK : 1;   // ws is >=1GB in practice

    dim3 g1(NCG / 256, nchunk);
    matvec_split<<<g1, 256, 0, stream>>>(x, (const f32x4*)W, (f32x4*)part);
    finalize<<<N_OUT / 256, 256, 0, stream>>>(
        part, nchunk, u, g_bar, ratio, out, sg);

    ew_pipe<<<EW_BLOCKS, 256, 0, stream>>>(
        x, (const f32x4*)E, (const f32x4*)R_hat, (const f32x4*)sg,
        Enew4, Rnew4);
}